// Round 12
// baseline (310.602 us; speedup 1.0000x reference)
//
#include <hip/hip_runtime.h>
#include <hip/hip_bf16.h>
#include <math.h>

#define BN_EPS 1e-5f
#define BN_BLOCKS 512

typedef __attribute__((ext_vector_type(8)))  short short8v;
typedef __attribute__((ext_vector_type(16))) float f32x16;

__device__ __forceinline__ unsigned short f2bf(float f){
  union { float f; unsigned u; } v; v.f = f;
  unsigned r = v.u + 0x7FFFu + ((v.u >> 16) & 1u);
  return (unsigned short)(r >> 16);
}
__device__ __forceinline__ float bf2f(unsigned short b){
  union { unsigned u; float f; } v; v.u = ((unsigned)b) << 16;
  return v.f;
}
__device__ __forceinline__ float2 bfpair(unsigned u){
  union { unsigned u; float f; } lo, hi;
  lo.u = u << 16;
  hi.u = u & 0xFFFF0000u;
  return make_float2(lo.f, hi.f);
}
__device__ __forceinline__ unsigned packbf(float a, float b){
  return (unsigned)f2bf(a) | ((unsigned)f2bf(b) << 16);
}

// ---------------- BatchNorm stats (two-stage, no atomics) ----------------
__global__ __launch_bounds__(256) void bn_part(const float* __restrict__ x,
                                               float* __restrict__ part, int total4){
  const float4* x4 = (const float4*)x;
  int stride = gridDim.x * blockDim.x;
  float4 s = make_float4(0.f,0.f,0.f,0.f);
  float4 q = make_float4(0.f,0.f,0.f,0.f);
  for (int idx = blockIdx.x*blockDim.x + threadIdx.x; idx < total4; idx += stride){
    float4 v = x4[idx];
    s.x += v.x; s.y += v.y; s.z += v.z; s.w += v.w;
    q.x += v.x*v.x; q.y += v.y*v.y; q.z += v.z*v.z; q.w += v.w*v.w;
  }
  __shared__ float4 shs[256], shq[256];
  shs[threadIdx.x] = s; shq[threadIdx.x] = q;
  __syncthreads();
  if (threadIdx.x < 32){
    int c4 = threadIdx.x;
    float4 ts = shs[c4], tq = shq[c4];
    #pragma unroll
    for (int j = 1; j < 8; ++j){
      float4 os = shs[c4 + j*32], oq = shq[c4 + j*32];
      ts.x += os.x; ts.y += os.y; ts.z += os.z; ts.w += os.w;
      tq.x += oq.x; tq.y += oq.y; tq.z += oq.z; tq.w += oq.w;
    }
    float* pb = part + (size_t)blockIdx.x * 256;
    *(float4*)(pb + c4*4)       = ts;
    *(float4*)(pb + 128 + c4*4) = tq;
  }
}

__global__ __launch_bounds__(256) void bn_reduce(const float* __restrict__ part,
                                                 const float* __restrict__ gamma,
                                                 const float* __restrict__ beta,
                                                 float* __restrict__ scale,
                                                 float* __restrict__ shift, int N){
  int t = threadIdx.x;
  float a0=0.f,a1=0.f,a2=0.f,a3=0.f,a4=0.f,a5=0.f,a6=0.f,a7=0.f;
  for (int b = 0; b < BN_BLOCKS; b += 8){
    a0 += part[(size_t)(b+0)*256 + t];
    a1 += part[(size_t)(b+1)*256 + t];
    a2 += part[(size_t)(b+2)*256 + t];
    a3 += part[(size_t)(b+3)*256 + t];
    a4 += part[(size_t)(b+4)*256 + t];
    a5 += part[(size_t)(b+5)*256 + t];
    a6 += part[(size_t)(b+6)*256 + t];
    a7 += part[(size_t)(b+7)*256 + t];
  }
  float acc = ((a0+a1)+(a2+a3)) + ((a4+a5)+(a6+a7));
  __shared__ float sh[256];
  sh[t] = acc;
  __syncthreads();
  if (t < 128){
    float mu  = sh[t] / (float)N;
    float var = sh[t+128] / (float)N - mu*mu;
    float sc  = gamma[t] * rsqrtf(var + BN_EPS);
    scale[t] = sc;
    shift[t] = beta[t] - mu*sc;
  }
}

// ================= CSR build via XCD-partitioned bucket sort =================
// Buckets: b = dst >> 8 (256 nodes each). x = blockIdx&7 partition label —
// A1 and A2 use IDENTICAL grid/stride so each edge maps to the same (x,b).

// ---- A1: histogram hist[x][b] ----
__global__ __launch_bounds__(256) void edge_hist(const int* __restrict__ dst,
                                                 int* __restrict__ hist, int E, int NB){
  __shared__ int lh[512];
  for (int i = threadIdx.x; i < NB; i += 256) lh[i] = 0;
  __syncthreads();
  int x = blockIdx.x & 7;
  int stride = gridDim.x * 256;
  for (int e = blockIdx.x*256 + threadIdx.x; e < E; e += stride)
    atomicAdd(&lh[dst[e] >> 8], 1);
  __syncthreads();
  for (int i = threadIdx.x; i < NB; i += 256)
    if (lh[i]) atomicAdd(&hist[x*NB + i], lh[i]);
}

// ---- scan: bucket bases + per-(x,b) cursors ----
__global__ __launch_bounds__(512) void bucket_scan(const int* __restrict__ hist,
                                                   int* __restrict__ cursor,
                                                   int* __restrict__ bbase, int NB, int E){
  __shared__ int tot[512];
  int t = threadIdx.x;
  int h[8]; int total = 0;
  if (t < NB){
    #pragma unroll
    for (int xx = 0; xx < 8; ++xx){ h[xx] = hist[xx*NB + t]; total += h[xx]; }
  }
  tot[t] = (t < NB) ? total : 0;
  __syncthreads();
  int v = tot[t];
  for (int d = 1; d < 512; d <<= 1){
    int u = (t >= d) ? tot[t-d] : 0;
    __syncthreads();
    tot[t] += u;
    __syncthreads();
  }
  if (t < NB){
    int base = tot[t] - v;
    bbase[t] = base;
    int run = base;
    #pragma unroll
    for (int xx = 0; xx < 8; ++xx){ cursor[xx*NB + t] = run; run += h[xx]; }
  }
  if (t == 0) bbase[NB] = E;
}

// ---- A2: scatter packed (dstlow<<24 | src) into per-(x,b) segments ----
__global__ __launch_bounds__(256) void edge_scatter(const int* __restrict__ src,
                                                    const int* __restrict__ dst,
                                                    int* __restrict__ cursor,
                                                    unsigned* __restrict__ ebuf, int E, int NB){
  int x = blockIdx.x & 7;
  int stride = gridDim.x * 256;
  for (int e = blockIdx.x*256 + threadIdx.x; e < E; e += stride){
    int d = dst[e];
    int b = d >> 8;
    int pos = atomicAdd(&cursor[x*NB + b], 1);
    ebuf[pos] = ((unsigned)(d & 255) << 24) | (unsigned)src[e];
  }
}

// ---- B: per-bucket LDS counting sort -> csrs + rowstart + dinv ----
__global__ __launch_bounds__(256) void bucket_sort(const unsigned* __restrict__ ebuf,
                                                   const int* __restrict__ bbase,
                                                   int* __restrict__ csrs,
                                                   int* __restrict__ rowstart,
                                                   float* __restrict__ dinv,
                                                   int N, int E, int NB){
  int b = blockIdx.x;
  int base = bbase[b];
  int end  = bbase[b+1];
  int len  = end - base;
  int tid = threadIdx.x;
  __shared__ int cnt[256];
  __shared__ int pref[256];
  cnt[tid] = 0;
  __syncthreads();
  for (int i = tid; i < len; i += 256)
    atomicAdd(&cnt[ebuf[base + i] >> 24], 1);
  __syncthreads();
  int v = cnt[tid];
  pref[tid] = v;
  __syncthreads();
  for (int d = 1; d < 256; d <<= 1){
    int u = (tid >= d) ? pref[tid-d] : 0;
    __syncthreads();
    pref[tid] += u;
    __syncthreads();
  }
  int excl = pref[tid] - v;
  int node = b*256 + tid;
  if (node < N){
    rowstart[node] = base + excl;
    dinv[node] = rsqrtf((float)v + 1.0f);   // +1 self loop
  }
  cnt[tid] = excl;   // reuse as cursor
  __syncthreads();
  for (int i = tid; i < len; i += 256){
    unsigned r = ebuf[base + i];
    int pos = atomicAdd(&cnt[r >> 24], 1);
    csrs[base + pos] = (int)(r & 0xFFFFFFu);
  }
  if (b == NB-1 && tid == 0) rowstart[N] = E;
}

__global__ void gbounds(const int* __restrict__ batch, int* __restrict__ gstart, int N, int G){
  int g = blockIdx.x*blockDim.x + threadIdx.x;
  if (g > G) return;
  int lo = 0, hi = N;
  while (lo < hi){ int mid = (lo+hi)>>1; if (batch[mid] < g) lo = mid+1; else hi = mid; }
  gstart[g] = lo;
}

// ---- W -> bf16 transposed Wt[l][c][k]; layer-0 gets BN scale folded in ----
__global__ void prep_w(const float* __restrict__ W0, const float* __restrict__ W1,
                       const float* __restrict__ W2, const float* __restrict__ scale,
                       unsigned short* __restrict__ Wh){
  int idx = blockIdx.x*blockDim.x + threadIdx.x;
  if (idx >= 3*16384) return;
  int l = idx >> 14, r = idx & 16383, c = r >> 7, k = r & 127;
  const float* W = (l==0) ? W0 : (l==1) ? W1 : W2;
  float v = W[k*128 + c];
  if (l == 0) v *= scale[k];
  Wh[idx] = f2bf(v);
}

// ---- layer-0 bias': b0 + shift @ W0 (BN shift folded) ----
__global__ __launch_bounds__(128) void prep_bias0(const float* __restrict__ b0,
                                                  const float* __restrict__ shift,
                                                  const float* __restrict__ W0,
                                                  float* __restrict__ bias0p){
  int j = threadIdx.x;
  __shared__ float sh[128];
  sh[j] = shift[j];
  __syncthreads();
  float s = b0[j];
  for (int c = 0; c < 128; ++c) s += sh[c] * W0[c*128 + j];
  bias0p[j] = s;
}

// ---------------- lean MFMA GEMM: C[N,128] (bf16) = A @ W_hi ----------------
template<int CVT>
__global__ __launch_bounds__(512) void gemm_mfma(
    const float* __restrict__ A32, const unsigned short* __restrict__ A16,
    const unsigned short* __restrict__ Bh, unsigned short* __restrict__ C, int N){
  __shared__ unsigned short Ah[64*128];
  int tid = threadIdx.x;
  int r0 = blockIdx.x * 64;
  int w = tid >> 6, lane = tid & 63;
  int rt = w & 1;
  int ct = (w >> 1) * 32;
  int lrow = 32*rt + (lane & 31);
  int khalf = lane >> 5;
  int c0 = ct + (lane & 31);
  const unsigned short* bh0 = Bh + (size_t)c0*128 + khalf*8;

  short8v bhf[8];
  #pragma unroll
  for (int s = 0; s < 8; ++s) bhf[s] = *(const short8v*)(bh0 + s*16);

  if (CVT){
    #pragma unroll
    for (int it = 0; it < 4; ++it){
      int idx = tid + it*512;
      int row = idx >> 5;
      int c4  = idx & 31;
      int r = r0 + row;
      float4 av = (r < N) ? *(const float4*)(A32 + (size_t)r*128 + c4*4)
                          : make_float4(0.f,0.f,0.f,0.f);
      int byte0 = (c4*8) ^ ((row & 15) << 4);
      uint2 p = make_uint2(packbf(av.x, av.y), packbf(av.z, av.w));
      *(uint2*)((char*)Ah + row*256 + byte0) = p;
    }
  } else {
    #pragma unroll
    for (int it = 0; it < 2; ++it){
      int idx = tid + it*512;
      int row = idx >> 4;
      int c8  = idx & 15;
      int r = r0 + row;
      uint4 v = (r < N) ? *(const uint4*)(A16 + (size_t)r*128 + c8*8)
                        : make_uint4(0,0,0,0);
      int byte0 = (c8*16) ^ ((row & 15) << 4);
      *(uint4*)((char*)Ah + row*256 + byte0) = v;
    }
  }
  __syncthreads();

  f32x16 acc = {};
  const char* AhB = (const char*)Ah + lrow*256;
  int sw = (lrow & 15) << 4;
  #pragma unroll
  for (int s = 0; s < 8; ++s){
    int abyte = (s*32 + khalf*16) ^ sw;
    short8v a = *(const short8v*)(AhB + abyte);
    acc = __builtin_amdgcn_mfma_f32_32x32x16_bf16(a, bhf[s], acc, 0, 0, 0);
  }

  #pragma unroll
  for (int r = 0; r < 16; ++r){
    int row = r0 + 32*rt + (r & 3) + 8*(r >> 2) + 4*khalf;
    if (row < N) C[(size_t)row*128 + c0] = f2bf(acc[r]);
  }
}

// ---------------- fused aggregation + bias + squash + attention ----------------
__global__ __launch_bounds__(256) void gather_squash(
    const unsigned short* __restrict__ m, const int* __restrict__ rowstart,
    const int* __restrict__ csrs, const float* __restrict__ dinv,
    const float* __restrict__ bias, const float* __restrict__ tar,
    unsigned short* __restrict__ h, float* __restrict__ attn, int N){
  int node = blockIdx.x*8 + (threadIdx.x >> 5);
  if (node >= N) return;
  int lane = threadIdx.x & 31;
  const uint2* m2 = (const uint2*)m;
  float dv = dinv[node];
  float sn = dv*dv;
  uint2 sv = m2[(size_t)node*32 + lane];
  float2 p0 = bfpair(sv.x), p1 = bfpair(sv.y);
  float a0 = p0.x*sn, a1 = p0.y*sn, a2 = p1.x*sn, a3 = p1.y*sn;
  int j0 = rowstart[node], j1 = rowstart[node+1];

  for (int base = j0; base < j1; base += 32){
    int cnt = j1 - base; if (cnt > 32) cnt = 32;
    int sidx = 0; float swt = 0.f;
    if (lane < cnt){
      sidx = csrs[base + lane];
      swt  = dinv[sidx] * dv;
    }
    int t = 0;
    for (; t + 4 <= cnt; t += 4){
      int s0 = __shfl(sidx, t, 32),   s1 = __shfl(sidx, t+1, 32);
      int s2 = __shfl(sidx, t+2, 32), s3 = __shfl(sidx, t+3, 32);
      float w0 = __shfl(swt, t, 32),   w1 = __shfl(swt, t+1, 32);
      float w2 = __shfl(swt, t+2, 32), w3 = __shfl(swt, t+3, 32);
      uint2 u0 = m2[(size_t)s0*32 + lane];
      uint2 u1 = m2[(size_t)s1*32 + lane];
      uint2 u2 = m2[(size_t)s2*32 + lane];
      uint2 u3 = m2[(size_t)s3*32 + lane];
      float2 q0, q1;
      q0 = bfpair(u0.x); q1 = bfpair(u0.y);
      a0 += w0*q0.x; a1 += w0*q0.y; a2 += w0*q1.x; a3 += w0*q1.y;
      q0 = bfpair(u1.x); q1 = bfpair(u1.y);
      a0 += w1*q0.x; a1 += w1*q0.y; a2 += w1*q1.x; a3 += w1*q1.y;
      q0 = bfpair(u2.x); q1 = bfpair(u2.y);
      a0 += w2*q0.x; a1 += w2*q0.y; a2 += w2*q1.x; a3 += w2*q1.y;
      q0 = bfpair(u3.x); q1 = bfpair(u3.y);
      a0 += w3*q0.x; a1 += w3*q0.y; a2 += w3*q1.x; a3 += w3*q1.y;
    }
    if (cnt - t >= 2){
      int s0 = __shfl(sidx, t, 32), s1 = __shfl(sidx, t+1, 32);
      float w0 = __shfl(swt, t, 32), w1 = __shfl(swt, t+1, 32);
      uint2 u0 = m2[(size_t)s0*32 + lane];
      uint2 u1 = m2[(size_t)s1*32 + lane];
      float2 q0 = bfpair(u0.x), q1 = bfpair(u0.y);
      a0 += w0*q0.x; a1 += w0*q0.y; a2 += w0*q1.x; a3 += w0*q1.y;
      q0 = bfpair(u1.x); q1 = bfpair(u1.y);
      a0 += w1*q0.x; a1 += w1*q0.y; a2 += w1*q1.x; a3 += w1*q1.y;
      t += 2;
    }
    if (t < cnt){
      int s0 = __shfl(sidx, t, 32);
      float w0 = __shfl(swt, t, 32);
      uint2 u0 = m2[(size_t)s0*32 + lane];
      float2 q0 = bfpair(u0.x), q1 = bfpair(u0.y);
      a0 += w0*q0.x; a1 += w0*q0.y; a2 += w0*q1.x; a3 += w0*q1.y;
    }
  }

  float4 bv = ((const float4*)bias)[lane];
  a0 += bv.x; a1 += bv.y; a2 += bv.z; a3 += bv.w;
  float n2 = a0*a0 + a1*a1 + a2*a2 + a3*a3;
  #pragma unroll
  for (int o = 16; o > 0; o >>= 1) n2 += __shfl_xor(n2, o);
  float sc = (n2/(1.f+n2)) * rsqrtf(n2 + 1e-12f);
  float h0 = a0*sc, h1 = a1*sc, h2 = a2*sc, h3 = a3*sc;
  ((uint2*)(h + (size_t)node*128))[lane] = make_uint2(packbf(h0,h1), packbf(h2,h3));
  float4 tv = ((const float4*)tar)[lane];
  float at = h0*tv.x + h1*tv.y + h2*tv.z + h3*tv.w;
  #pragma unroll
  for (int o = 16; o > 0; o >>= 1) at += __shfl_xor(at, o);
  if (lane == 0) attn[node] = at;
}

// ---------------- per-graph readout (wsum / mean / max), accumulated ----------------
__global__ __launch_bounds__(1024) void readout(const unsigned short* __restrict__ h,
                                                const float* __restrict__ attn,
                                                const int* __restrict__ gstart,
                                                float* __restrict__ grep){
  int g = blockIdx.x;
  int t   = threadIdx.x & 63;
  int grp = threadIdx.x >> 6;
  int a = gstart[g], b = gstart[g+1];
  float wsx = 0.f, wsy = 0.f, smx_ = 0.f, smy_ = 0.f;
  float mxx = -INFINITY, mxy = -INFINITY;
  for (int n = a + grp; n < b; n += 16){
    unsigned u = ((const unsigned*)(h + (size_t)n*128))[t];
    float2 v = bfpair(u);
    float at = attn[n];
    wsx += at*v.x; wsy += at*v.y;
    smx_ += v.x;  smy_ += v.y;
    mxx = fmaxf(mxx, v.x); mxy = fmaxf(mxy, v.y);
  }
  __shared__ float2 sws[16][64], ssm[16][64], smx[16][64];
  sws[grp][t] = make_float2(wsx, wsy);
  ssm[grp][t] = make_float2(smx_, smy_);
  smx[grp][t] = make_float2(mxx, mxy);
  __syncthreads();
  if (grp == 0){
    #pragma unroll
    for (int j = 1; j < 16; ++j){
      float2 ow = sws[j][t], os = ssm[j][t], om = smx[j][t];
      wsx += ow.x; wsy += ow.y;
      smx_ += os.x; smy_ += os.y;
      mxx = fmaxf(mxx, om.x); mxy = fmaxf(mxy, om.y);
    }
    int cnt = b - a;
    float inv = 1.f / fmaxf((float)cnt, 1.f);
    if (cnt == 0){ mxx = 0.f; mxy = 0.f; }
    grep[(size_t)g*384 + t*2]           += wsx;
    grep[(size_t)g*384 + t*2 + 1]       += wsy;
    grep[(size_t)g*384 + 128 + t*2]     += smx_*inv;
    grep[(size_t)g*384 + 128 + t*2 + 1] += smy_*inv;
    grep[(size_t)g*384 + 256 + t*2]     += mxx;
    grep[(size_t)g*384 + 256 + t*2 + 1] += mxy;
  }
}

// ---------------- classifier head + log_softmax ----------------
__global__ __launch_bounds__(128) void classify(const float* __restrict__ grep,
                                                const float* __restrict__ w1, const float* __restrict__ b1,
                                                const float* __restrict__ w2, const float* __restrict__ b2,
                                                float* __restrict__ out){
  int g = blockIdx.x, t = threadIdx.x;
  __shared__ float gr[384];
  for (int i = t; i < 384; i += 128) gr[i] = grep[(size_t)g*384 + i];
  __syncthreads();
  float z = b1[t];
  for (int k = 0; k < 384; ++k) z += gr[k]*w1[k*128 + t];
  z = fmaxf(z, 0.f);
  float c0 = z*w2[t*2 + 0], c1 = z*w2[t*2 + 1];
  #pragma unroll
  for (int o = 32; o > 0; o >>= 1){ c0 += __shfl_xor(c0, o); c1 += __shfl_xor(c1, o); }
  __shared__ float r0s[2], r1s[2];
  if ((t & 63) == 0){ r0s[t>>6] = c0; r1s[t>>6] = c1; }
  __syncthreads();
  if (t == 0){
    float z0 = r0s[0] + r0s[1] + b2[0];
    float z1 = r1s[0] + r1s[1] + b2[1];
    float mm = fmaxf(z0, z1);
    float lse = mm + logf(expf(z0-mm) + expf(z1-mm));
    out[g*2 + 0] = z0 - lse;
    out[g*2 + 1] = z1 - lse;
  }
}

extern "C" void kernel_launch(void* const* d_in, const int* in_sizes, int n_in,
                              void* d_out, int out_size, void* d_ws, size_t ws_size,
                              hipStream_t stream) {
  const float* x     = (const float*)d_in[0];
  const int*   ei    = (const int*)d_in[1];
  const int*   batch = (const int*)d_in[2];
  const float* gamma = (const float*)d_in[3];
  const float* beta  = (const float*)d_in[4];
  const float* W0    = (const float*)d_in[5];
  const float* b0    = (const float*)d_in[6];
  const float* W1    = (const float*)d_in[7];
  const float* b1    = (const float*)d_in[8];
  const float* W2    = (const float*)d_in[9];
  const float* b2    = (const float*)d_in[10];
  const float* tar   = (const float*)d_in[11];
  const float* l1w   = (const float*)d_in[12];
  const float* l1b   = (const float*)d_in[13];
  const float* l2w   = (const float*)d_in[14];
  const float* l2b   = (const float*)d_in[15];
  float* out = (float*)d_out;

  int N = in_sizes[0] / 128;
  int E = in_sizes[1] / 2;
  int G = out_size / 2;
  const int* srcp = ei;
  const int* dstp = ei + E;

  char* wsb = (char*)d_ws;
  size_t off = 0;
  auto alloc = [&](size_t bytes)->char*{
    char* p = wsb + off; off += (bytes + 255) & ~(size_t)255; return p;
  };
  unsigned short* h = (unsigned short*)alloc((size_t)N*128*2);
  unsigned short* m = (unsigned short*)alloc((size_t)N*128*2);
  float* attn    = (float*)alloc((size_t)N*4);
  float* dinv    = (float*)alloc((size_t)N*4);
  int*   rowst   = (int*)  alloc((size_t)(N+1)*4);
  int*   csrs    = (int*)  alloc((size_t)E*4);
  unsigned* ebuf = (unsigned*)alloc((size_t)E*4);
  int*   hist    = (int*)  alloc(8*512*4);
  int*   cursor  = (int*)  alloc(8*512*4);
  int*   bbase   = (int*)  alloc(513*4);
  int*   gstart  = (int*)  alloc((size_t)(G+1)*4);
  float* grep    = (float*)alloc((size_t)G*384*4);
  float* stats   = (float*)alloc(2*128*4);
  float* bias0p  = (float*)alloc(128*4);
  float* part    = (float*)alloc((size_t)BN_BLOCKS*256*4);
  unsigned short* Wh = (unsigned short*)alloc(3*16384*2);
  (void)ws_size;

  float* scale  = stats;
  float* shift  = stats + 128;

  int NB = (N + 255) >> 8;                 // <=512 for N<=131072
  hipMemsetAsync(hist, 0, (size_t)8*NB*4, stream);
  hipMemsetAsync(grep, 0, (size_t)G*384*4, stream);

  // --- CSR build via bucket sort (replaces count_deg/scans/fill_csr/dinv_k) ---
  const int GE = 1024;  // MUST match between edge_hist and edge_scatter
  edge_hist<<<GE, 256, 0, stream>>>(dstp, hist, E, NB);
  bucket_scan<<<1, 512, 0, stream>>>(hist, cursor, bbase, NB, E);
  edge_scatter<<<GE, 256, 0, stream>>>(srcp, dstp, cursor, ebuf, E, NB);
  bucket_sort<<<NB, 256, 0, stream>>>(ebuf, bbase, csrs, rowst, dinv, N, E, NB);
  gbounds<<<(G+1+255)/256, 256, 0, stream>>>(batch, gstart, N, G);

  // --- BatchNorm stats, then fold into W0'/bias0' ---
  bn_part<<<BN_BLOCKS, 256, 0, stream>>>(x, part, N*32);
  bn_reduce<<<1, 256, 0, stream>>>(part, gamma, beta, scale, shift, N);
  prep_w<<<(3*16384+255)/256, 256, 0, stream>>>(W0, W1, W2, scale, Wh);
  prep_bias0<<<1, 128, 0, stream>>>(b0, shift, W0, bias0p);

  const float* bs[3] = {bias0p, b1, b2};
  int nb64 = (N + 63) / 64;
  for (int l = 0; l < 3; ++l){
    if (l == 0)
      gemm_mfma<1><<<nb64, 512, 0, stream>>>(x, nullptr, Wh, m, N);
    else
      gemm_mfma<0><<<nb64, 512, 0, stream>>>(nullptr, h, Wh + l*16384, m, N);
    gather_squash<<<(N+7)/8, 256, 0, stream>>>(m, rowst, csrs, dinv, bs[l], tar + l*128, h, attn, N);
    readout<<<G, 1024, 0, stream>>>(h, attn, gstart, grep);
  }
  classify<<<G, 128, 0, stream>>>(grep, l1w, l1b, l2w, l2b, out);
}

// Round 13
// 277.485 us; speedup vs baseline: 1.1193x; 1.1193x over previous
//
#include <hip/hip_runtime.h>
#include <hip/hip_bf16.h>
#include <math.h>

#define BN_EPS 1e-5f
#define BN_BLOCKS 512
#define NCHUNK 256

typedef __attribute__((ext_vector_type(8)))  short short8v;
typedef __attribute__((ext_vector_type(16))) float f32x16;

__device__ __forceinline__ unsigned short f2bf(float f){
  union { float f; unsigned u; } v; v.f = f;
  unsigned r = v.u + 0x7FFFu + ((v.u >> 16) & 1u);
  return (unsigned short)(r >> 16);
}
__device__ __forceinline__ float bf2f(unsigned short b){
  union { unsigned u; float f; } v; v.u = ((unsigned)b) << 16;
  return v.f;
}
__device__ __forceinline__ float2 bfpair(unsigned u){
  union { unsigned u; float f; } lo, hi;
  lo.u = u << 16;
  hi.u = u & 0xFFFF0000u;
  return make_float2(lo.f, hi.f);
}
__device__ __forceinline__ unsigned packbf(float a, float b){
  return (unsigned)f2bf(a) | ((unsigned)f2bf(b) << 16);
}

// ---------------- BatchNorm stats (two-stage, no atomics) ----------------
__global__ __launch_bounds__(256) void bn_part(const float* __restrict__ x,
                                               float* __restrict__ part, int total4){
  const float4* x4 = (const float4*)x;
  int stride = gridDim.x * blockDim.x;
  float4 s = make_float4(0.f,0.f,0.f,0.f);
  float4 q = make_float4(0.f,0.f,0.f,0.f);
  for (int idx = blockIdx.x*blockDim.x + threadIdx.x; idx < total4; idx += stride){
    float4 v = x4[idx];
    s.x += v.x; s.y += v.y; s.z += v.z; s.w += v.w;
    q.x += v.x*v.x; q.y += v.y*v.y; q.z += v.z*v.z; q.w += v.w*v.w;
  }
  __shared__ float4 shs[256], shq[256];
  shs[threadIdx.x] = s; shq[threadIdx.x] = q;
  __syncthreads();
  if (threadIdx.x < 32){
    int c4 = threadIdx.x;
    float4 ts = shs[c4], tq = shq[c4];
    #pragma unroll
    for (int j = 1; j < 8; ++j){
      float4 os = shs[c4 + j*32], oq = shq[c4 + j*32];
      ts.x += os.x; ts.y += os.y; ts.z += os.z; ts.w += os.w;
      tq.x += oq.x; tq.y += oq.y; tq.z += oq.z; tq.w += oq.w;
    }
    float* pb = part + (size_t)blockIdx.x * 256;
    *(float4*)(pb + c4*4)       = ts;
    *(float4*)(pb + 128 + c4*4) = tq;
  }
}

__global__ __launch_bounds__(256) void bn_reduce(const float* __restrict__ part,
                                                 const float* __restrict__ gamma,
                                                 const float* __restrict__ beta,
                                                 float* __restrict__ scale,
                                                 float* __restrict__ shift, int N){
  int t = threadIdx.x;
  float a0=0.f,a1=0.f,a2=0.f,a3=0.f,a4=0.f,a5=0.f,a6=0.f,a7=0.f;
  for (int b = 0; b < BN_BLOCKS; b += 8){
    a0 += part[(size_t)(b+0)*256 + t];
    a1 += part[(size_t)(b+1)*256 + t];
    a2 += part[(size_t)(b+2)*256 + t];
    a3 += part[(size_t)(b+3)*256 + t];
    a4 += part[(size_t)(b+4)*256 + t];
    a5 += part[(size_t)(b+5)*256 + t];
    a6 += part[(size_t)(b+6)*256 + t];
    a7 += part[(size_t)(b+7)*256 + t];
  }
  float acc = ((a0+a1)+(a2+a3)) + ((a4+a5)+(a6+a7));
  __shared__ float sh[256];
  sh[t] = acc;
  __syncthreads();
  if (t < 128){
    float mu  = sh[t] / (float)N;
    float var = sh[t+128] / (float)N - mu*mu;
    float sc  = gamma[t] * rsqrtf(var + BN_EPS);
    scale[t] = sc;
    shift[t] = beta[t] - mu*sc;
  }
}

// ========== CSR build: zero-global-atomic 3-phase bucket scatter ==========
// Bucket b = dst>>8 (256 nodes). Chunk c = block over E/NCHUNK edges.

// ---- P1: per-chunk LDS histogram -> hist2[c][b] (non-atomic row write) ----
__global__ __launch_bounds__(256) void chunk_hist(const int* __restrict__ dst,
                                                  int* __restrict__ hist2,
                                                  int E, int NB, int CH){
  __shared__ int lh[512];
  for (int i = threadIdx.x; i < NB; i += 256) lh[i] = 0;
  __syncthreads();
  int c = blockIdx.x;
  int e0 = c*CH, e1 = min(e0 + CH, E);
  for (int e = e0 + threadIdx.x; e < e1; e += 256)
    atomicAdd(&lh[dst[e] >> 8], 1);
  __syncthreads();
  for (int i = threadIdx.x; i < NB; i += 256)
    hist2[c*NB + i] = lh[i];
}

// ---- P2: exact offsets offs2[c][b] + bucket bases (1 block) ----
__global__ __launch_bounds__(512) void chunk_scan(const int* __restrict__ hist2,
                                                  int* __restrict__ offs2,
                                                  int* __restrict__ bbase,
                                                  int NB, int E){
  __shared__ int tot[512];
  int b = threadIdx.x;
  int total = 0;
  if (b < NB){
    for (int c = 0; c < NCHUNK; c += 8){
      int h0 = hist2[(c+0)*NB + b], h1 = hist2[(c+1)*NB + b];
      int h2 = hist2[(c+2)*NB + b], h3 = hist2[(c+3)*NB + b];
      int h4 = hist2[(c+4)*NB + b], h5 = hist2[(c+5)*NB + b];
      int h6 = hist2[(c+6)*NB + b], h7 = hist2[(c+7)*NB + b];
      total += ((h0+h1)+(h2+h3)) + ((h4+h5)+(h6+h7));
    }
  }
  tot[b] = (b < NB) ? total : 0;
  __syncthreads();
  int v = tot[b];
  for (int d = 1; d < 512; d <<= 1){
    int u = (b >= d) ? tot[b-d] : 0;
    __syncthreads();
    tot[b] += u;
    __syncthreads();
  }
  if (b < NB){
    int base = tot[b] - v;   // exclusive
    bbase[b] = base;
    int run = base;
    for (int c = 0; c < NCHUNK; c += 8){
      int h0 = hist2[(c+0)*NB + b], h1 = hist2[(c+1)*NB + b];
      int h2 = hist2[(c+2)*NB + b], h3 = hist2[(c+3)*NB + b];
      int h4 = hist2[(c+4)*NB + b], h5 = hist2[(c+5)*NB + b];
      int h6 = hist2[(c+6)*NB + b], h7 = hist2[(c+7)*NB + b];
      offs2[(c+0)*NB + b] = run; run += h0;
      offs2[(c+1)*NB + b] = run; run += h1;
      offs2[(c+2)*NB + b] = run; run += h2;
      offs2[(c+3)*NB + b] = run; run += h3;
      offs2[(c+4)*NB + b] = run; run += h4;
      offs2[(c+5)*NB + b] = run; run += h5;
      offs2[(c+6)*NB + b] = run; run += h6;
      offs2[(c+7)*NB + b] = run; run += h7;
    }
  }
  if (b == 0) bbase[NB] = E;
}

// ---- P3: scatter via LDS cursors (no global atomics) ----
__global__ __launch_bounds__(256) void chunk_scatter(const int* __restrict__ src,
                                                     const int* __restrict__ dst,
                                                     const int* __restrict__ offs2,
                                                     unsigned* __restrict__ ebuf,
                                                     int E, int NB, int CH){
  __shared__ int lcur[512];
  int c = blockIdx.x;
  for (int i = threadIdx.x; i < NB; i += 256) lcur[i] = offs2[c*NB + i];
  __syncthreads();
  int e0 = c*CH, e1 = min(e0 + CH, E);
  for (int e = e0 + threadIdx.x; e < e1; e += 256){
    int d = dst[e];
    int b = d >> 8;
    int pos = atomicAdd(&lcur[b], 1);   // LDS atomic — cheap
    ebuf[pos] = ((unsigned)(d & 255) << 24) | (unsigned)src[e];
  }
}

// ---- per-bucket LDS counting sort -> csrs + rowstart + dinv ----
__global__ __launch_bounds__(256) void bucket_sort(const unsigned* __restrict__ ebuf,
                                                   const int* __restrict__ bbase,
                                                   int* __restrict__ csrs,
                                                   int* __restrict__ rowstart,
                                                   float* __restrict__ dinv,
                                                   int N, int E, int NB){
  int b = blockIdx.x;
  int base = bbase[b];
  int end  = bbase[b+1];
  int len  = end - base;
  int tid = threadIdx.x;
  __shared__ int cnt[256];
  __shared__ int pref[256];
  cnt[tid] = 0;
  __syncthreads();
  for (int i = tid; i < len; i += 256)
    atomicAdd(&cnt[ebuf[base + i] >> 24], 1);
  __syncthreads();
  int v = cnt[tid];
  pref[tid] = v;
  __syncthreads();
  for (int d = 1; d < 256; d <<= 1){
    int u = (tid >= d) ? pref[tid-d] : 0;
    __syncthreads();
    pref[tid] += u;
    __syncthreads();
  }
  int excl = pref[tid] - v;
  int node = b*256 + tid;
  if (node < N){
    rowstart[node] = base + excl;
    dinv[node] = rsqrtf((float)v + 1.0f);
  }
  cnt[tid] = excl;
  __syncthreads();
  for (int i = tid; i < len; i += 256){
    unsigned r = ebuf[base + i];
    int pos = atomicAdd(&cnt[r >> 24], 1);
    csrs[base + pos] = (int)(r & 0xFFFFFFu);
  }
  if (b == NB-1 && tid == 0) rowstart[N] = E;
}

__global__ void gbounds(const int* __restrict__ batch, int* __restrict__ gstart, int N, int G){
  int g = blockIdx.x*blockDim.x + threadIdx.x;
  if (g > G) return;
  int lo = 0, hi = N;
  while (lo < hi){ int mid = (lo+hi)>>1; if (batch[mid] < g) lo = mid+1; else hi = mid; }
  gstart[g] = lo;
}

// ---- W -> bf16 transposed Wt[l][c][k]; layer-0 gets BN scale folded in ----
__global__ void prep_w(const float* __restrict__ W0, const float* __restrict__ W1,
                       const float* __restrict__ W2, const float* __restrict__ scale,
                       unsigned short* __restrict__ Wh){
  int idx = blockIdx.x*blockDim.x + threadIdx.x;
  if (idx >= 3*16384) return;
  int l = idx >> 14, r = idx & 16383, c = r >> 7, k = r & 127;
  const float* W = (l==0) ? W0 : (l==1) ? W1 : W2;
  float v = W[k*128 + c];
  if (l == 0) v *= scale[k];
  Wh[idx] = f2bf(v);
}

// ---- layer-0 bias': b0 + shift @ W0 (BN shift folded) ----
__global__ __launch_bounds__(128) void prep_bias0(const float* __restrict__ b0,
                                                  const float* __restrict__ shift,
                                                  const float* __restrict__ W0,
                                                  float* __restrict__ bias0p){
  int j = threadIdx.x;
  __shared__ float sh[128];
  sh[j] = shift[j];
  __syncthreads();
  float s = b0[j];
  for (int c = 0; c < 128; ++c) s += sh[c] * W0[c*128 + j];
  bias0p[j] = s;
}

// ---------------- lean MFMA GEMM: C[N,128] (bf16) = A @ W_hi ----------------
template<int CVT>
__global__ __launch_bounds__(512) void gemm_mfma(
    const float* __restrict__ A32, const unsigned short* __restrict__ A16,
    const unsigned short* __restrict__ Bh, unsigned short* __restrict__ C, int N){
  __shared__ unsigned short Ah[64*128];
  int tid = threadIdx.x;
  int r0 = blockIdx.x * 64;
  int w = tid >> 6, lane = tid & 63;
  int rt = w & 1;
  int ct = (w >> 1) * 32;
  int lrow = 32*rt + (lane & 31);
  int khalf = lane >> 5;
  int c0 = ct + (lane & 31);
  const unsigned short* bh0 = Bh + (size_t)c0*128 + khalf*8;

  short8v bhf[8];
  #pragma unroll
  for (int s = 0; s < 8; ++s) bhf[s] = *(const short8v*)(bh0 + s*16);

  if (CVT){
    #pragma unroll
    for (int it = 0; it < 4; ++it){
      int idx = tid + it*512;
      int row = idx >> 5;
      int c4  = idx & 31;
      int r = r0 + row;
      float4 av = (r < N) ? *(const float4*)(A32 + (size_t)r*128 + c4*4)
                          : make_float4(0.f,0.f,0.f,0.f);
      int byte0 = (c4*8) ^ ((row & 15) << 4);
      uint2 p = make_uint2(packbf(av.x, av.y), packbf(av.z, av.w));
      *(uint2*)((char*)Ah + row*256 + byte0) = p;
    }
  } else {
    #pragma unroll
    for (int it = 0; it < 2; ++it){
      int idx = tid + it*512;
      int row = idx >> 4;
      int c8  = idx & 15;
      int r = r0 + row;
      uint4 v = (r < N) ? *(const uint4*)(A16 + (size_t)r*128 + c8*8)
                        : make_uint4(0,0,0,0);
      int byte0 = (c8*16) ^ ((row & 15) << 4);
      *(uint4*)((char*)Ah + row*256 + byte0) = v;
    }
  }
  __syncthreads();

  f32x16 acc = {};
  const char* AhB = (const char*)Ah + lrow*256;
  int sw = (lrow & 15) << 4;
  #pragma unroll
  for (int s = 0; s < 8; ++s){
    int abyte = (s*32 + khalf*16) ^ sw;
    short8v a = *(const short8v*)(AhB + abyte);
    acc = __builtin_amdgcn_mfma_f32_32x32x16_bf16(a, bhf[s], acc, 0, 0, 0);
  }

  #pragma unroll
  for (int r = 0; r < 16; ++r){
    int row = r0 + 32*rt + (r & 3) + 8*(r >> 2) + 4*khalf;
    if (row < N) C[(size_t)row*128 + c0] = f2bf(acc[r]);
  }
}

// ---------------- fused aggregation + bias + squash + attention ----------------
__global__ __launch_bounds__(256) void gather_squash(
    const unsigned short* __restrict__ m, const int* __restrict__ rowstart,
    const int* __restrict__ csrs, const float* __restrict__ dinv,
    const float* __restrict__ bias, const float* __restrict__ tar,
    unsigned short* __restrict__ h, float* __restrict__ attn, int N){
  int node = blockIdx.x*8 + (threadIdx.x >> 5);
  if (node >= N) return;
  int lane = threadIdx.x & 31;
  const uint2* m2 = (const uint2*)m;
  float dv = dinv[node];
  float sn = dv*dv;
  uint2 sv = m2[(size_t)node*32 + lane];
  float2 p0 = bfpair(sv.x), p1 = bfpair(sv.y);
  float a0 = p0.x*sn, a1 = p0.y*sn, a2 = p1.x*sn, a3 = p1.y*sn;
  int j0 = rowstart[node], j1 = rowstart[node+1];

  for (int base = j0; base < j1; base += 32){
    int cnt = j1 - base; if (cnt > 32) cnt = 32;
    int sidx = 0; float swt = 0.f;
    if (lane < cnt){
      sidx = csrs[base + lane];
      swt  = dinv[sidx] * dv;
    }
    int t = 0;
    for (; t + 4 <= cnt; t += 4){
      int s0 = __shfl(sidx, t, 32),   s1 = __shfl(sidx, t+1, 32);
      int s2 = __shfl(sidx, t+2, 32), s3 = __shfl(sidx, t+3, 32);
      float w0 = __shfl(swt, t, 32),   w1 = __shfl(swt, t+1, 32);
      float w2 = __shfl(swt, t+2, 32), w3 = __shfl(swt, t+3, 32);
      uint2 u0 = m2[(size_t)s0*32 + lane];
      uint2 u1 = m2[(size_t)s1*32 + lane];
      uint2 u2 = m2[(size_t)s2*32 + lane];
      uint2 u3 = m2[(size_t)s3*32 + lane];
      float2 q0, q1;
      q0 = bfpair(u0.x); q1 = bfpair(u0.y);
      a0 += w0*q0.x; a1 += w0*q0.y; a2 += w0*q1.x; a3 += w0*q1.y;
      q0 = bfpair(u1.x); q1 = bfpair(u1.y);
      a0 += w1*q0.x; a1 += w1*q0.y; a2 += w1*q1.x; a3 += w1*q1.y;
      q0 = bfpair(u2.x); q1 = bfpair(u2.y);
      a0 += w2*q0.x; a1 += w2*q0.y; a2 += w2*q1.x; a3 += w2*q1.y;
      q0 = bfpair(u3.x); q1 = bfpair(u3.y);
      a0 += w3*q0.x; a1 += w3*q0.y; a2 += w3*q1.x; a3 += w3*q1.y;
    }
    if (cnt - t >= 2){
      int s0 = __shfl(sidx, t, 32), s1 = __shfl(sidx, t+1, 32);
      float w0 = __shfl(swt, t, 32), w1 = __shfl(swt, t+1, 32);
      uint2 u0 = m2[(size_t)s0*32 + lane];
      uint2 u1 = m2[(size_t)s1*32 + lane];
      float2 q0 = bfpair(u0.x), q1 = bfpair(u0.y);
      a0 += w0*q0.x; a1 += w0*q0.y; a2 += w0*q1.x; a3 += w0*q1.y;
      q0 = bfpair(u1.x); q1 = bfpair(u1.y);
      a0 += w1*q0.x; a1 += w1*q0.y; a2 += w1*q1.x; a3 += w1*q1.y;
      t += 2;
    }
    if (t < cnt){
      int s0 = __shfl(sidx, t, 32);
      float w0 = __shfl(swt, t, 32);
      uint2 u0 = m2[(size_t)s0*32 + lane];
      float2 q0 = bfpair(u0.x), q1 = bfpair(u0.y);
      a0 += w0*q0.x; a1 += w0*q0.y; a2 += w0*q1.x; a3 += w0*q1.y;
    }
  }

  float4 bv = ((const float4*)bias)[lane];
  a0 += bv.x; a1 += bv.y; a2 += bv.z; a3 += bv.w;
  float n2 = a0*a0 + a1*a1 + a2*a2 + a3*a3;
  #pragma unroll
  for (int o = 16; o > 0; o >>= 1) n2 += __shfl_xor(n2, o);
  float sc = (n2/(1.f+n2)) * rsqrtf(n2 + 1e-12f);
  float h0 = a0*sc, h1 = a1*sc, h2 = a2*sc, h3 = a3*sc;
  ((uint2*)(h + (size_t)node*128))[lane] = make_uint2(packbf(h0,h1), packbf(h2,h3));
  float4 tv = ((const float4*)tar)[lane];
  float at = h0*tv.x + h1*tv.y + h2*tv.z + h3*tv.w;
  #pragma unroll
  for (int o = 16; o > 0; o >>= 1) at += __shfl_xor(at, o);
  if (lane == 0) attn[node] = at;
}

// ---------------- per-graph readout (wsum / mean / max), accumulated ----------------
__global__ __launch_bounds__(1024) void readout(const unsigned short* __restrict__ h,
                                                const float* __restrict__ attn,
                                                const int* __restrict__ gstart,
                                                float* __restrict__ grep){
  int g = blockIdx.x;
  int t   = threadIdx.x & 63;
  int grp = threadIdx.x >> 6;
  int a = gstart[g], b = gstart[g+1];
  float wsx = 0.f, wsy = 0.f, smx_ = 0.f, smy_ = 0.f;
  float mxx = -INFINITY, mxy = -INFINITY;
  for (int n = a + grp; n < b; n += 16){
    unsigned u = ((const unsigned*)(h + (size_t)n*128))[t];
    float2 v = bfpair(u);
    float at = attn[n];
    wsx += at*v.x; wsy += at*v.y;
    smx_ += v.x;  smy_ += v.y;
    mxx = fmaxf(mxx, v.x); mxy = fmaxf(mxy, v.y);
  }
  __shared__ float2 sws[16][64], ssm[16][64], smx[16][64];
  sws[grp][t] = make_float2(wsx, wsy);
  ssm[grp][t] = make_float2(smx_, smy_);
  smx[grp][t] = make_float2(mxx, mxy);
  __syncthreads();
  if (grp == 0){
    #pragma unroll
    for (int j = 1; j < 16; ++j){
      float2 ow = sws[j][t], os = ssm[j][t], om = smx[j][t];
      wsx += ow.x; wsy += ow.y;
      smx_ += os.x; smy_ += os.y;
      mxx = fmaxf(mxx, om.x); mxy = fmaxf(mxy, om.y);
    }
    int cnt = b - a;
    float inv = 1.f / fmaxf((float)cnt, 1.f);
    if (cnt == 0){ mxx = 0.f; mxy = 0.f; }
    grep[(size_t)g*384 + t*2]           += wsx;
    grep[(size_t)g*384 + t*2 + 1]       += wsy;
    grep[(size_t)g*384 + 128 + t*2]     += smx_*inv;
    grep[(size_t)g*384 + 128 + t*2 + 1] += smy_*inv;
    grep[(size_t)g*384 + 256 + t*2]     += mxx;
    grep[(size_t)g*384 + 256 + t*2 + 1] += mxy;
  }
}

// ---------------- classifier head + log_softmax ----------------
__global__ __launch_bounds__(128) void classify(const float* __restrict__ grep,
                                                const float* __restrict__ w1, const float* __restrict__ b1,
                                                const float* __restrict__ w2, const float* __restrict__ b2,
                                                float* __restrict__ out){
  int g = blockIdx.x, t = threadIdx.x;
  __shared__ float gr[384];
  for (int i = t; i < 384; i += 128) gr[i] = grep[(size_t)g*384 + i];
  __syncthreads();
  float z = b1[t];
  for (int k = 0; k < 384; ++k) z += gr[k]*w1[k*128 + t];
  z = fmaxf(z, 0.f);
  float c0 = z*w2[t*2 + 0], c1 = z*w2[t*2 + 1];
  #pragma unroll
  for (int o = 32; o > 0; o >>= 1){ c0 += __shfl_xor(c0, o); c1 += __shfl_xor(c1, o); }
  __shared__ float r0s[2], r1s[2];
  if ((t & 63) == 0){ r0s[t>>6] = c0; r1s[t>>6] = c1; }
  __syncthreads();
  if (t == 0){
    float z0 = r0s[0] + r0s[1] + b2[0];
    float z1 = r1s[0] + r1s[1] + b2[1];
    float mm = fmaxf(z0, z1);
    float lse = mm + logf(expf(z0-mm) + expf(z1-mm));
    out[g*2 + 0] = z0 - lse;
    out[g*2 + 1] = z1 - lse;
  }
}

extern "C" void kernel_launch(void* const* d_in, const int* in_sizes, int n_in,
                              void* d_out, int out_size, void* d_ws, size_t ws_size,
                              hipStream_t stream) {
  const float* x     = (const float*)d_in[0];
  const int*   ei    = (const int*)d_in[1];
  const int*   batch = (const int*)d_in[2];
  const float* gamma = (const float*)d_in[3];
  const float* beta  = (const float*)d_in[4];
  const float* W0    = (const float*)d_in[5];
  const float* b0    = (const float*)d_in[6];
  const float* W1    = (const float*)d_in[7];
  const float* b1    = (const float*)d_in[8];
  const float* W2    = (const float*)d_in[9];
  const float* b2    = (const float*)d_in[10];
  const float* tar   = (const float*)d_in[11];
  const float* l1w   = (const float*)d_in[12];
  const float* l1b   = (const float*)d_in[13];
  const float* l2w   = (const float*)d_in[14];
  const float* l2b   = (const float*)d_in[15];
  float* out = (float*)d_out;

  int N = in_sizes[0] / 128;
  int E = in_sizes[1] / 2;
  int G = out_size / 2;
  const int* srcp = ei;
  const int* dstp = ei + E;

  char* wsb = (char*)d_ws;
  size_t off = 0;
  auto alloc = [&](size_t bytes)->char*{
    char* p = wsb + off; off += (bytes + 255) & ~(size_t)255; return p;
  };
  unsigned short* h = (unsigned short*)alloc((size_t)N*128*2);
  unsigned short* m = (unsigned short*)alloc((size_t)N*128*2);
  float* attn    = (float*)alloc((size_t)N*4);
  float* dinv    = (float*)alloc((size_t)N*4);
  int*   rowst   = (int*)  alloc((size_t)(N+1)*4);
  int*   csrs    = (int*)  alloc((size_t)E*4);
  unsigned* ebuf = (unsigned*)alloc((size_t)E*4);
  int*   hist2   = (int*)  alloc((size_t)NCHUNK*512*4);
  int*   offs2   = (int*)  alloc((size_t)NCHUNK*512*4);
  int*   bbase   = (int*)  alloc(513*4);
  int*   gstart  = (int*)  alloc((size_t)(G+1)*4);
  float* grep    = (float*)alloc((size_t)G*384*4);
  float* stats   = (float*)alloc(2*128*4);
  float* bias0p  = (float*)alloc(128*4);
  float* part    = (float*)alloc((size_t)BN_BLOCKS*256*4);
  unsigned short* Wh = (unsigned short*)alloc(3*16384*2);
  (void)ws_size;

  float* scale  = stats;
  float* shift  = stats + 128;

  int NB = (N + 255) >> 8;                 // 391 for N=100000 (<=512)
  int CH = (E + NCHUNK - 1) / NCHUNK;      // edges per chunk
  hipMemsetAsync(grep, 0, (size_t)G*384*4, stream);

  // --- CSR build: 3-phase zero-global-atomic scatter + bucket sort ---
  chunk_hist<<<NCHUNK, 256, 0, stream>>>(dstp, hist2, E, NB, CH);
  chunk_scan<<<1, 512, 0, stream>>>(hist2, offs2, bbase, NB, E);
  chunk_scatter<<<NCHUNK, 256, 0, stream>>>(srcp, dstp, offs2, ebuf, E, NB, CH);
  bucket_sort<<<NB, 256, 0, stream>>>(ebuf, bbase, csrs, rowst, dinv, N, E, NB);
  gbounds<<<(G+1+255)/256, 256, 0, stream>>>(batch, gstart, N, G);

  // --- BatchNorm stats, then fold into W0'/bias0' ---
  bn_part<<<BN_BLOCKS, 256, 0, stream>>>(x, part, N*32);
  bn_reduce<<<1, 256, 0, stream>>>(part, gamma, beta, scale, shift, N);
  prep_w<<<(3*16384+255)/256, 256, 0, stream>>>(W0, W1, W2, scale, Wh);
  prep_bias0<<<1, 128, 0, stream>>>(b0, shift, W0, bias0p);

  const float* bs[3] = {bias0p, b1, b2};
  int nb64 = (N + 63) / 64;
  for (int l = 0; l < 3; ++l){
    if (l == 0)
      gemm_mfma<1><<<nb64, 512, 0, stream>>>(x, nullptr, Wh, m, N);
    else
      gemm_mfma<0><<<nb64, 512, 0, stream>>>(nullptr, h, Wh + l*16384, m, N);
    gather_squash<<<(N+7)/8, 256, 0, stream>>>(m, rowst, csrs, dinv, bs[l], tar + l*128, h, attn, N);
    readout<<<G, 1024, 0, stream>>>(h, attn, gstart, grep);
  }
  classify<<<G, 128, 0, stream>>>(grep, l1w, l1b, l2w, l2b, out);
}